// Round 4
// baseline (225.285 us; speedup 1.0000x reference)
//
#include <hip/hip_runtime.h>

// Paged KV-cache scatter write (float32).
//   kv_pages: (4096, 16, 16, 128)  -> out (full copy + scatter)
//   new_k, new_v: (8192, 8, 128)
//   t_pages, t_slots: (8192,) int32
// Semantics: out[p,s,0::2,:] = new_k[i]; out[p,s,1::2,:] = new_v[i]
// with numpy last-write-wins on duplicate (p,s) and mode='drop' bounds.
//
// Structure: winner pass (atomicMax of token idx per row) resolves duplicate
// (page,slot) deterministically, then one fused copy-or-scatter streaming pass.
// R4: plain loads/stores (the 6.77 TB/s fill + 6.29 TB/s m13 copy recipe —
// nt hints were neutral-to-negative), 16 rows/block, 32-bit offsets.

#define NUM_PAGES 4096
#define PAGE_SIZE 16
#define KV_HEADS 8
#define HEAD_SIZE 128
#define N_TOKENS 8192
#define NUM_ROWS (NUM_PAGES * PAGE_SIZE)       // 65536 (page,slot) rows
#define ROW_F4 (2 * KV_HEADS * HEAD_SIZE / 4)  // 512 float4 per row (8 KiB)
#define ROWS_PER_BLOCK 16                      // 128 KiB per block, grid 4096

typedef float f32x4 __attribute__((ext_vector_type(4)));

__global__ void kv_winners_kernel(const int* __restrict__ t_pages,
                                  const int* __restrict__ t_slots,
                                  int* __restrict__ winner) {
    int i = blockIdx.x * blockDim.x + threadIdx.x;
    if (i >= N_TOKENS) return;
    int p = t_pages[i];
    int s = t_slots[i];
    // mode='drop': out-of-range indices are ignored
    if ((unsigned)p < (unsigned)NUM_PAGES && (unsigned)s < (unsigned)PAGE_SIZE) {
        atomicMax(&winner[p * PAGE_SIZE + s], i);   // last token index wins
    }
}

__global__ __launch_bounds__(256)
void kv_write_kernel(const f32x4* __restrict__ kv_pages,
                     const float* __restrict__ new_k,
                     const float* __restrict__ new_v,
                     const int* __restrict__ winner,
                     f32x4* __restrict__ out) {
    const unsigned row0 = blockIdx.x * ROWS_PER_BLOCK;
    const unsigned tid  = threadIdx.x;

    // Winners for this block: uniform addresses -> scalar loads.
    int w[ROWS_PER_BLOCK];
    #pragma unroll
    for (int r = 0; r < ROWS_PER_BLOCK; ++r) w[r] = winner[row0 + r];

    // Per-thread fixed lane geometry (2 f32x4 per row at t and t+256).
    for (int r = 0; r < ROWS_PER_BLOCK; ++r) {
        const unsigned base4 = (row0 + r) * (unsigned)ROW_F4;   // < 2^25, fits 32-bit
        if (w[r] < 0) {
            // untouched row: straight streaming copy
            #pragma unroll
            for (unsigned t = tid; t < ROW_F4; t += 256) {
                out[base4 + t] = kv_pages[base4 + t];
            }
        } else {
            // overwritten row: interleave new_k (even heads) / new_v (odd heads)
            const unsigned wi = (unsigned)w[r];
            #pragma unroll
            for (unsigned t = tid; t < ROW_F4; t += 256) {
                unsigned head = t >> 5;                  // 32 f32x4 per head
                unsigned d4   = t & 31;
                const float* src = (head & 1) ? new_v : new_k;
                unsigned off = (wi * KV_HEADS + (head >> 1)) * HEAD_SIZE + d4 * 4;  // < 2^23
                out[base4 + t] = *reinterpret_cast<const f32x4*>(src + off);
            }
        }
    }
}

extern "C" void kernel_launch(void* const* d_in, const int* in_sizes, int n_in,
                              void* d_out, int out_size, void* d_ws, size_t ws_size,
                              hipStream_t stream) {
    const float* kv_pages = (const float*)d_in[0];
    const float* new_k    = (const float*)d_in[1];
    const float* new_v    = (const float*)d_in[2];
    const int*   t_pages  = (const int*)d_in[3];
    const int*   t_slots  = (const int*)d_in[4];
    float*       out      = (float*)d_out;
    int*         winner   = (int*)d_ws;             // 65536 ints = 256 KiB

    // winner[row] = -1 (0xFFFFFFFF) for "untouched"
    (void)hipMemsetAsync(winner, 0xFF, NUM_ROWS * sizeof(int), stream);

    kv_winners_kernel<<<(N_TOKENS + 255) / 256, 256, 0, stream>>>(t_pages, t_slots, winner);

    kv_write_kernel<<<NUM_ROWS / ROWS_PER_BLOCK, 256, 0, stream>>>(
        (const f32x4*)kv_pages, new_k, new_v, winner, (f32x4*)out);
}

// Round 5
// 209.345 us; speedup vs baseline: 1.0761x; 1.0761x over previous
//
#include <hip/hip_runtime.h>

// Paged KV-cache scatter write (float32).
//   kv_pages: (4096, 16, 16, 128)  -> out (full copy + scatter)
//   new_k, new_v: (8192, 8, 128)
//   t_pages, t_slots: (8192,) int32
// Semantics: out[p,s,0::2,:] = new_k[i]; out[p,s,1::2,:] = new_v[i]
// with numpy last-write-wins on duplicate (p,s) and mode='drop' bounds.
//
// Structure: winner pass (atomicMax of token idx per row) resolves duplicate
// (page,slot) deterministically, then one fused copy-or-scatter streaming pass.
// R5: branchless wave-uniform pointer select per row -> 16 independent nt
// loads in flight per thread (MLP 2->16), then 16 nt stores. ROWS_PER_BLOCK=8
// (best known, R3). nt on loads+stores (R3 recipe; R4 showed dropping nt hurt).

#define NUM_PAGES 4096
#define PAGE_SIZE 16
#define KV_HEADS 8
#define HEAD_SIZE 128
#define N_TOKENS 8192
#define NUM_ROWS (NUM_PAGES * PAGE_SIZE)       // 65536 (page,slot) rows
#define ROW_F4 (2 * KV_HEADS * HEAD_SIZE / 4)  // 512 f32x4 per row (8 KiB)
#define ROWS_PER_BLOCK 8                       // 64 KiB per block, grid 8192
#define HEAD_F4 (HEAD_SIZE / 4)                // 32 f32x4 per head
#define TOK_F4 (KV_HEADS * HEAD_SIZE / 4)      // 256 f32x4 per token (per k or v)

typedef float f32x4 __attribute__((ext_vector_type(4)));

__global__ void kv_winners_kernel(const int* __restrict__ t_pages,
                                  const int* __restrict__ t_slots,
                                  int* __restrict__ winner) {
    int i = blockIdx.x * blockDim.x + threadIdx.x;
    if (i >= N_TOKENS) return;
    int p = t_pages[i];
    int s = t_slots[i];
    // mode='drop': out-of-range indices are ignored
    if ((unsigned)p < (unsigned)NUM_PAGES && (unsigned)s < (unsigned)PAGE_SIZE) {
        atomicMax(&winner[p * PAGE_SIZE + s], i);   // last token index wins
    }
}

__global__ __launch_bounds__(256)
void kv_write_kernel(const f32x4* __restrict__ kv_pages,
                     const f32x4* __restrict__ new_k,
                     const f32x4* __restrict__ new_v,
                     const int* __restrict__ winner,
                     f32x4* __restrict__ out) {
    const unsigned row0 = blockIdx.x * ROWS_PER_BLOCK;
    const unsigned tid  = threadIdx.x;

    // Per-thread element geometry: this thread owns elements t0=tid, t1=tid+256
    // of each row. head/d4 are compile-time-derivable per element slot.
    const f32x4* src[ROWS_PER_BLOCK * 2];
    #pragma unroll
    for (int r = 0; r < ROWS_PER_BLOCK; ++r) {
        const int w = winner[row0 + r];            // wave-uniform
        const int wi = w < 0 ? 0 : w;              // keep pointer math sane
        const size_t base4 = (size_t)(row0 + r) * ROW_F4;
        #pragma unroll
        for (int e = 0; e < 2; ++e) {
            const unsigned t    = tid + e * 256;
            const unsigned head = t >> 5;
            const unsigned d4   = t & 31;
            const f32x4* scat = ((head & 1) ? new_v : new_k)
                              + (size_t)wi * TOK_F4 + (head >> 1) * HEAD_F4 + d4;
            // wave-uniform select: no divergence, coalescing preserved
            src[r * 2 + e] = (w < 0) ? (kv_pages + base4 + t) : scat;
        }
    }

    // Phase 1: issue all 16 independent loads (deep MLP, no branches between)
    f32x4 v[ROWS_PER_BLOCK * 2];
    #pragma unroll
    for (int i = 0; i < ROWS_PER_BLOCK * 2; ++i)
        v[i] = __builtin_nontemporal_load(src[i]);

    // Phase 2: stores (contiguous 1 KiB per wave per element slot)
    #pragma unroll
    for (int r = 0; r < ROWS_PER_BLOCK; ++r) {
        const size_t base4 = (size_t)(row0 + r) * ROW_F4;
        __builtin_nontemporal_store(v[r * 2 + 0], &out[base4 + tid]);
        __builtin_nontemporal_store(v[r * 2 + 1], &out[base4 + tid + 256]);
    }
}

extern "C" void kernel_launch(void* const* d_in, const int* in_sizes, int n_in,
                              void* d_out, int out_size, void* d_ws, size_t ws_size,
                              hipStream_t stream) {
    const float* kv_pages = (const float*)d_in[0];
    const float* new_k    = (const float*)d_in[1];
    const float* new_v    = (const float*)d_in[2];
    const int*   t_pages  = (const int*)d_in[3];
    const int*   t_slots  = (const int*)d_in[4];
    float*       out      = (float*)d_out;
    int*         winner   = (int*)d_ws;             // 65536 ints = 256 KiB

    // winner[row] = -1 (0xFFFFFFFF) for "untouched"
    (void)hipMemsetAsync(winner, 0xFF, NUM_ROWS * sizeof(int), stream);

    kv_winners_kernel<<<(N_TOKENS + 255) / 256, 256, 0, stream>>>(t_pages, t_slots, winner);

    kv_write_kernel<<<NUM_ROWS / ROWS_PER_BLOCK, 256, 0, stream>>>(
        (const f32x4*)kv_pages, (const f32x4*)new_k, (const f32x4*)new_v,
        winner, (f32x4*)out);
}